// Round 1
// 2176.187 us; speedup vs baseline: 1.4726x; 1.4726x over previous
//
#include <hip/hip_runtime.h>
#include <hip/hip_bf16.h>

// Model dims
#define V    32000
#define D    1024
#define NL   2
#define DI   2048
#define NS   16       // d_state
#define DT_R 64
#define KC   4
#define OUT  32000
#define BB   4
#define LL   1024
#define M4   (BB*LL)  // 4096 rows

// chunked scan
#define CCH  16       // chunks along L
#define LCH  (LL/CCH) // 64 timesteps per chunk

typedef __bf16 bf16x8 __attribute__((ext_vector_type(8)));
typedef float  f32x4  __attribute__((ext_vector_type(4)));

__device__ __forceinline__ void async_copy16(const void* g, void* l) {
    __builtin_amdgcn_global_load_lds(
        (const __attribute__((address_space(1))) void*)g,
        (__attribute__((address_space(3))) void*)l, 16, 0, 0);
}

__device__ __forceinline__ float b2f(__hip_bfloat16 x) { return __bfloat162float(x); }

// ---------------- embedding gather: h[m][c] = emb[ids[m]][c] (fp32) -------
__global__ __launch_bounds__(256) void k_embed(const int* __restrict__ ids,
                                               const float* __restrict__ emb,
                                               float* __restrict__ h) {
    int m = blockIdx.x;
    int id = ids[m];
    const float4* src = (const float4*)(emb + (size_t)id * D);
    float4* dst = (float4*)(h + (size_t)m * D);
    dst[threadIdx.x] = src[threadIdx.x];  // 256 * 4 = 1024 = D
}

// ---------------- fp32 -> bf16 transpose: in[R][C] -> out[C][R] -----------
__global__ __launch_bounds__(256) void k_transpose(const float* __restrict__ in,
                                                   __hip_bfloat16* __restrict__ out,
                                                   int R, int C) {
    __shared__ __hip_bfloat16 t[32][33];
    int c0 = blockIdx.x * 32, r0 = blockIdx.y * 32;
    int x = threadIdx.x & 31;
    int y0 = threadIdx.x >> 5;  // 0..7
    for (int yy = y0; yy < 32; yy += 8) {
        int r = r0 + yy, c = c0 + x;
        t[yy][x] = (r < R && c < C) ? __float2bfloat16(in[(size_t)r * C + c])
                                    : __float2bfloat16(0.f);
    }
    __syncthreads();
    for (int yy = y0; yy < 32; yy += 8) {
        int c = c0 + yy, r = r0 + x;
        if (c < C && r < R) out[(size_t)c * R + r] = t[x][yy];
    }
}

// ---------------- fp32 -> bf16 cast (head_w, already [N,K]) ---------------
__global__ __launch_bounds__(256) void k_cast(const float* __restrict__ in,
                                              __hip_bfloat16* __restrict__ out, int n) {
    int i = (blockIdx.x * 256 + threadIdx.x) * 4;
    if (i < n) {
        float4 v = *(const float4*)(in + i);
        out[i + 0] = __float2bfloat16(v.x);
        out[i + 1] = __float2bfloat16(v.y);
        out[i + 2] = __float2bfloat16(v.z);
        out[i + 3] = __float2bfloat16(v.w);
    }
}

// ---------------- rmsnorm: fp32 in -> bf16 out ----------------------------
__global__ __launch_bounds__(256) void k_rmsnorm(const float* __restrict__ x,
                                                 const float* __restrict__ w,
                                                 __hip_bfloat16* __restrict__ out) {
    int m = blockIdx.x;
    const float* row = x + (size_t)m * D;
    float ss = 0.f;
    for (int c = threadIdx.x; c < D; c += 256) { float v = row[c]; ss += v * v; }
    for (int o = 32; o; o >>= 1) ss += __shfl_down(ss, o, 64);
    __shared__ float red[4];
    if ((threadIdx.x & 63) == 0) red[threadIdx.x >> 6] = ss;
    __syncthreads();
    float scale = rsqrtf((red[0] + red[1] + red[2] + red[3]) * (1.f / D) + 1e-5f);
    __hip_bfloat16* dst = out + (size_t)m * D;
    for (int c = threadIdx.x; c < D; c += 256)
        dst[c] = __float2bfloat16(row[c] * scale * w[c]);
}

// ---------------- causal depthwise conv (K=4) + silu ----------------------
__global__ __launch_bounds__(256) void k_conv(const __hip_bfloat16* __restrict__ xz,
                                              const float* __restrict__ cw,
                                              const float* __restrict__ cb,
                                              __hip_bfloat16* __restrict__ xc) {
    int idx = blockIdx.x * 256 + threadIdx.x;  // m*DI + d
    int m = idx >> 11, d = idx & (DI - 1);
    int b = m >> 10, t = m & (LL - 1);
    float acc = cb[d];
#pragma unroll
    for (int j = 0; j < KC; j++) {
        int tt = t - (KC - 1) + j;
        if (tt >= 0)
            acc += b2f(xz[(size_t)(b * LL + tt) * (2 * DI) + d]) * cw[d * KC + j];
    }
    float s = acc / (1.f + expf(-acc));
    xc[idx] = __float2bfloat16(s);
}

// ---------------- selective scan: chunk-parallel linear recurrence --------
// s_t = a_t * s_{t-1} + b_t  with  a_t = exp(delta_t * A),  b_t = delta_t*x_t*B_t
// Phase 1: per chunk, local scan from 0 -> (a_prod, s_local_final)
// Phase 2: exclusive scan over chunk summaries -> s0 per chunk (in-place, .x)
// Phase 3: re-run each chunk seeded with s0, reduce over n, write yact.
// Block geometry (phases 1,3): 256 thr = 16 d x 16 n; grid = B * DI/16 * CCH.

__global__ __launch_bounds__(256) void k_scan1(const float* __restrict__ delta,
                                               const __hip_bfloat16* __restrict__ xc,
                                               const float* __restrict__ dbl,
                                               const float* __restrict__ A_log,
                                               float2* __restrict__ summ) {
    int c = blockIdx.x & (CCH - 1);
    int rest = blockIdx.x >> 4;
    int b = rest >> 7;
    int d = ((rest & 127) << 4) + (threadIdx.x >> 4);
    int n = threadIdx.x & 15;
    float A2 = -expf(A_log[d * NS + n]) * 1.44269504f;  // A * log2(e)
    float s = 0.f, sumd = 0.f;
    size_t rb = (size_t)b * LL + (size_t)c * LCH;
    for (int t = 0; t < LCH; t++) {
        size_t r = rb + t;
        float dlt = delta[r * DI + d];
        float x = b2f(xc[r * DI + d]);
        float bt = dbl[r * 96 + DT_R + n];
        s = exp2f(dlt * A2) * s + (dlt * x) * bt;
        sumd += dlt;
    }
    float ap = exp2f(A2 * sumd);  // = prod_t exp(dlt_t * A)
    summ[(((size_t)b * DI + d) * NS + n) * CCH + c] = make_float2(ap, s);
}

__global__ __launch_bounds__(256) void k_scan2(float2* __restrict__ summ) {
    int b = blockIdx.x >> 7;
    int d = ((blockIdx.x & 127) << 4) + (threadIdx.x >> 4);
    int n = threadIdx.x & 15;
    size_t base = (((size_t)b * DI + d) * NS + n) * CCH;
    float s0 = 0.f;
#pragma unroll
    for (int cc = 0; cc < CCH; cc++) {
        float2 v = summ[base + cc];
        reinterpret_cast<float*>(summ + base + cc)[0] = s0;  // overwrite .x with s0
        s0 = v.x * s0 + v.y;
    }
}

__global__ __launch_bounds__(256) void k_scan3(const float* __restrict__ delta,
                                               const __hip_bfloat16* __restrict__ xc,
                                               const float* __restrict__ dbl,
                                               const float* __restrict__ A_log,
                                               const float* __restrict__ Dskip,
                                               const __hip_bfloat16* __restrict__ xz,
                                               const float2* __restrict__ summ,
                                               __hip_bfloat16* __restrict__ yact) {
    int c = blockIdx.x & (CCH - 1);
    int rest = blockIdx.x >> 4;
    int b = rest >> 7;
    int d = ((rest & 127) << 4) + (threadIdx.x >> 4);
    int n = threadIdx.x & 15;
    float A2 = -expf(A_log[d * NS + n]) * 1.44269504f;
    float Dv = Dskip[d];
    float s = summ[(((size_t)b * DI + d) * NS + n) * CCH + c].x;  // s0 for this chunk
    size_t rb = (size_t)b * LL + (size_t)c * LCH;
    for (int t = 0; t < LCH; t++) {
        size_t r = rb + t;
        float dlt = delta[r * DI + d];
        float x = b2f(xc[r * DI + d]);
        float bt = dbl[r * 96 + DT_R + n];
        float ct = dbl[r * 96 + DT_R + NS + n];
        s = exp2f(dlt * A2) * s + (dlt * x) * bt;
        float p = s * ct;
        p += __shfl_xor(p, 8);
        p += __shfl_xor(p, 4);
        p += __shfl_xor(p, 2);
        p += __shfl_xor(p, 1);
        if (n == 0) {
            float z = b2f(xz[r * (2 * DI) + DI + d]);
            float g = z / (1.f + expf(-z));
            yact[r * DI + d] = __float2bfloat16((p + Dv * x) * g);
        }
    }
}

// ---------------- MFMA GEMM: C[M,N] = A[M,K] @ BT[N,K]^T ------------------
// m97 structure: 128x128 tile, BK=32, 4 waves (2x2 of 64x64), global_load_lds.
// EPI: 0 = bf16 store to outB
//      1 = fp32 store to outF + bf16 copy of cols<64 to aux (dt_low)
//      2 = softplus(c + bias[n]) -> fp32 outF (delta)
//      3 = outF[m][n] += c (residual h update)
//      4 = fp32 store to outF (logits)
template <int EPI>
__global__ __launch_bounds__(256) void k_gemm(const __hip_bfloat16* __restrict__ A,
                                              const __hip_bfloat16* __restrict__ BT,
                                              int M, int N, int K, int lda, int ldb,
                                              float* __restrict__ outF,
                                              __hip_bfloat16* __restrict__ outB, int ldo,
                                              const float* __restrict__ bias,
                                              __hip_bfloat16* __restrict__ aux) {
    __shared__ __align__(16) __bf16 sA[128 * 32];
    __shared__ __align__(16) __bf16 sB[128 * 32];
    const int tid = threadIdx.x;
    const int m0 = blockIdx.y * 128;
    const int n0 = blockIdx.x * 128;
    const int lane = tid & 63;
    const int wid = tid >> 6;
    const int wm = (wid >> 1) * 64;
    const int wn = (wid & 1) * 64;
    const int l16 = lane & 15;
    const int quad = lane >> 4;

    f32x4 acc[4][4] = {};

    const int li0 = tid, li1 = tid + 256;
    const int rA0 = li0 >> 2, ko0 = (li0 & 3) * 8;
    const int rA1 = li1 >> 2, ko1 = (li1 & 3) * 8;
    int nb0 = n0 + rA0; if (nb0 >= N) nb0 = N - 1;
    int nb1 = n0 + rA1; if (nb1 >= N) nb1 = N - 1;

    const __hip_bfloat16* Ap0 = A + (size_t)(m0 + rA0) * lda + ko0;
    const __hip_bfloat16* Ap1 = A + (size_t)(m0 + rA1) * lda + ko1;
    const __hip_bfloat16* Bp0 = BT + (size_t)nb0 * ldb + ko0;
    const __hip_bfloat16* Bp1 = BT + (size_t)nb1 * ldb + ko1;

    for (int kb = 0; kb < K; kb += 32) {
        async_copy16(Ap0 + kb, sA + li0 * 8);
        async_copy16(Ap1 + kb, sA + li1 * 8);
        async_copy16(Bp0 + kb, sB + li0 * 8);
        async_copy16(Bp1 + kb, sB + li1 * 8);
        __syncthreads();

        bf16x8 av[4], bv[4];
#pragma unroll
        for (int i = 0; i < 4; i++)
            av[i] = *(const bf16x8*)(sA + (wm + i * 16 + l16) * 32 + quad * 8);
#pragma unroll
        for (int j = 0; j < 4; j++)
            bv[j] = *(const bf16x8*)(sB + (wn + j * 16 + l16) * 32 + quad * 8);
#pragma unroll
        for (int i = 0; i < 4; i++)
#pragma unroll
            for (int j = 0; j < 4; j++)
                acc[i][j] = __builtin_amdgcn_mfma_f32_16x16x32_bf16(av[i], bv[j], acc[i][j], 0, 0, 0);
        __syncthreads();
    }

#pragma unroll
    for (int i = 0; i < 4; i++) {
        int rbase = m0 + wm + i * 16 + quad * 4;
#pragma unroll
        for (int j = 0; j < 4; j++) {
            int col = n0 + wn + j * 16 + l16;
            if (col < N) {
#pragma unroll
                for (int r = 0; r < 4; r++) {
                    int row = rbase + r;
                    float c = acc[i][j][r];
                    if (EPI == 0) {
                        outB[(size_t)row * ldo + col] = __float2bfloat16(c);
                    } else if (EPI == 1) {
                        outF[(size_t)row * ldo + col] = c;
                        if (col < DT_R) aux[(size_t)row * DT_R + col] = __float2bfloat16(c);
                    } else if (EPI == 2) {
                        float v = c + bias[col];
                        outF[(size_t)row * ldo + col] = (v > 20.f) ? v : log1pf(expf(v));
                    } else if (EPI == 3) {
                        outF[(size_t)row * ldo + col] += c;
                    } else {
                        outF[(size_t)row * ldo + col] = c;
                    }
                }
            }
        }
    }
}

extern "C" void kernel_launch(void* const* d_in, const int* in_sizes, int n_in,
                              void* d_out, int out_size, void* d_ws, size_t ws_size,
                              hipStream_t stream) {
    const int*   ids      = (const int*)d_in[0];
    const float* emb      = (const float*)d_in[1];
    const float* norm_w   = (const float*)d_in[2];
    const float* in_proj  = (const float*)d_in[3];
    const float* conv_w   = (const float*)d_in[4];
    const float* conv_b   = (const float*)d_in[5];
    const float* x_proj   = (const float*)d_in[6];
    const float* dt_w     = (const float*)d_in[7];
    const float* dt_b     = (const float*)d_in[8];
    const float* A_log    = (const float*)d_in[9];
    const float* D_skip   = (const float*)d_in[10];
    const float* out_proj = (const float*)d_in[11];
    const float* final_nw = (const float*)d_in[12];
    const float* head_w   = (const float*)d_in[13];
    float*       out      = (float*)d_out;

    char* ws = (char*)d_ws;
    size_t off = 0;
    auto alloc = [&](size_t bytes) { char* p = ws + off; off += (bytes + 255) & ~(size_t)255; return p; };

    float*          h     = (float*)alloc((size_t)M4 * D * 4);
    __hip_bfloat16* xn    = (__hip_bfloat16*)alloc((size_t)M4 * D * 2);
    __hip_bfloat16* xz    = (__hip_bfloat16*)alloc((size_t)M4 * 2 * DI * 2);
    __hip_bfloat16* xc    = (__hip_bfloat16*)alloc((size_t)M4 * DI * 2);
    float*          dbl   = (float*)alloc((size_t)M4 * 96 * 4);
    __hip_bfloat16* dtlow = (__hip_bfloat16*)alloc((size_t)M4 * DT_R * 2);
    float*          delta = (float*)alloc((size_t)M4 * DI * 4);
    __hip_bfloat16* yact  = (__hip_bfloat16*)alloc((size_t)M4 * DI * 2);
    __hip_bfloat16* hn    = (__hip_bfloat16*)alloc((size_t)M4 * D * 2);
    __hip_bfloat16* wT1   = (__hip_bfloat16*)alloc((size_t)(2 * DI) * D * 2);  // in_projT [4096,1024]
    __hip_bfloat16* wT2   = (__hip_bfloat16*)alloc((size_t)96 * DI * 2);       // x_projT  [96,2048]
    __hip_bfloat16* wT3   = (__hip_bfloat16*)alloc((size_t)DI * DT_R * 2);     // dt_wT    [2048,64]
    __hip_bfloat16* wT4   = (__hip_bfloat16*)alloc((size_t)D * DI * 2);        // out_projT[1024,2048]
    // head bf16 copy: alias the (dead by then) xz..delta region (86 MB >= 65.6 MB)
    __hip_bfloat16* wHead = (__hip_bfloat16*)xz;
    // scan chunk summaries: B*DI*NS*CCH float2 = 16 MB. Aliases hn (8MB) + wT1
    // (8MB), which are contiguous (both 256B-multiple allocs) and dead during
    // the scan: wT1 is consumed by the xz GEMM earlier in the layer and
    // re-transposed next layer; hn is written only after both layers.
    float2*         summ  = (float2*)hn;

    dim3 tb(256);

    k_embed<<<M4, tb, 0, stream>>>(ids, emb, h);

    for (int l = 0; l < NL; l++) {
        k_transpose<<<dim3(128, 32), tb, 0, stream>>>(in_proj + (size_t)l * D * 2 * DI, wT1, D, 2 * DI);
        k_transpose<<<dim3(3, 64),   tb, 0, stream>>>(x_proj + (size_t)l * DI * 96, wT2, DI, 96);
        k_transpose<<<dim3(64, 2),   tb, 0, stream>>>(dt_w + (size_t)l * DT_R * DI, wT3, DT_R, DI);
        k_transpose<<<dim3(32, 64),  tb, 0, stream>>>(out_proj + (size_t)l * DI * D, wT4, DI, D);

        k_rmsnorm<<<M4, tb, 0, stream>>>(h, norm_w + (size_t)l * D, xn);

        // xz = xn @ in_proj  [4096 x 4096], K=1024
        k_gemm<0><<<dim3(32, 32), tb, 0, stream>>>(xn, wT1, M4, 2 * DI, D, D, D,
                                                   nullptr, xz, 2 * DI, nullptr, nullptr);

        k_conv<<<M4 * DI / 256, tb, 0, stream>>>(xz, conv_w + (size_t)l * DI * KC,
                                                 conv_b + (size_t)l * DI, xc);

        // dbl = xc @ x_proj  [4096 x 96], K=2048 (+ bf16 dt_low)
        k_gemm<1><<<dim3(1, 32), tb, 0, stream>>>(xc, wT2, M4, 96, DI, DI, DI,
                                                  dbl, nullptr, 96, nullptr, dtlow);

        // delta = softplus(dt_low @ dt_w + dt_b)  [4096 x 2048], K=64
        k_gemm<2><<<dim3(16, 32), tb, 0, stream>>>(dtlow, wT3, M4, DI, DT_R, DT_R, DT_R,
                                                   delta, nullptr, DI, dt_b + (size_t)l * DI, nullptr);

        // chunk-parallel selective scan (3 phases)
        k_scan1<<<BB * (DI / 16) * CCH, tb, 0, stream>>>(delta, xc, dbl,
                                                         A_log + (size_t)l * DI * NS, summ);
        k_scan2<<<BB * (DI / 16), tb, 0, stream>>>(summ);
        k_scan3<<<BB * (DI / 16) * CCH, tb, 0, stream>>>(delta, xc, dbl,
                                                         A_log + (size_t)l * DI * NS,
                                                         D_skip + (size_t)l * DI, xz, summ, yact);

        // h += yact @ out_proj  [4096 x 1024], K=2048
        k_gemm<3><<<dim3(8, 32), tb, 0, stream>>>(yact, wT4, M4, D, DI, DI, DI,
                                                  h, nullptr, D, nullptr, nullptr);
    }

    k_rmsnorm<<<M4, tb, 0, stream>>>(h, final_nw, hn);

    // head_w is [OUT, D] row-major = [N, K] — cast to bf16, no transpose
    k_cast<<<(OUT * D / 4 + 255) / 256, tb, 0, stream>>>(head_w, wHead, OUT * D);

    // logits = hn @ head_w^T  [4096 x 32000], K=1024
    k_gemm<4><<<dim3(OUT / 128, 32), tb, 0, stream>>>(hn, wHead, M4, OUT, D, D, D,
                                                      out, nullptr, OUT, nullptr, nullptr);
}